// Round 1
// baseline (2208.045 us; speedup 1.0000x reference)
//
#include <hip/hip_runtime.h>
#include <math.h>

#define BS 8
#define CIN 64
#define COUT 64
#define SDIM 512
#define NBANK 4
#define DSZ 32               // spatial dim (D=H=W=32)
#define SPATIAL (DSZ*DSZ*DSZ)
#define NTAP 27
constexpr float EPS = 1e-8f;

// ws layout (floats): mw[BS*COUT*CIN*27] | fwt[BS*4] | mod[BS*CIN]
#define MW_ELEMS (BS*COUT*CIN*NTAP)

// ---------------------------------------------------------------------------
// Kernel 0: per-sample style vectors. grid=BS blocks, 64 threads.
//   fwt[b][n] = softmax_n(w[b]·filter_w[n] + filter_b[n])
//   mod[b][c] = w[b]·mod_w[c] + mod_b[c]
// ---------------------------------------------------------------------------
__global__ void prep_style(const float* __restrict__ w,
                           const float* __restrict__ filter_w,
                           const float* __restrict__ filter_b,
                           const float* __restrict__ mod_w,
                           const float* __restrict__ mod_b,
                           float* __restrict__ fwt,
                           float* __restrict__ mod) {
    const int b = blockIdx.x;
    const int t = threadIdx.x;            // 0..63
    const float* wb = w + b * SDIM;
    __shared__ float lg[NBANK];

    if (t < NBANK) {
        float s = filter_b[t];
        const float* fr = filter_w + t * SDIM;
        for (int j = 0; j < SDIM; ++j) s += wb[j] * fr[j];
        lg[t] = s;
    }
    __syncthreads();
    if (t == 0) {
        float m = lg[0];
        for (int n = 1; n < NBANK; ++n) m = fmaxf(m, lg[n]);
        float e[NBANK];
        float s = 0.0f;
        for (int n = 0; n < NBANK; ++n) { e[n] = expf(lg[n] - m); s += e[n]; }
        for (int n = 0; n < NBANK; ++n) fwt[b * NBANK + n] = e[n] / s;
    }
    // modulation, one channel per lane
    {
        float s = mod_b[t];
        const float* mr = mod_w + t * SDIM;
        for (int j = 0; j < SDIM; ++j) s += wb[j] * mr[j];
        mod[b * CIN + t] = s;
    }
}

// ---------------------------------------------------------------------------
// Kernel 1: blended + modulated + demodulated weights.
// grid=(COUT, BS), 64 threads (lane = ic).
//   mw[b][oc][ic][tap] = demod(b,oc) * mod[b][ic] * sum_n fwt[b][n]*bank[n][oc][ic][tap]
// ---------------------------------------------------------------------------
__global__ void prep_weights(const float* __restrict__ bank,
                             const float* __restrict__ fwt,
                             const float* __restrict__ mod,
                             float* __restrict__ mw) {
    const int oc = blockIdx.x;
    const int b  = blockIdx.y;
    const int ic = threadIdx.x;           // 0..63

    const float f0 = fwt[b * NBANK + 0];
    const float f1 = fwt[b * NBANK + 1];
    const float f2 = fwt[b * NBANK + 2];
    const float f3 = fwt[b * NBANK + 3];
    const float m  = mod[b * CIN + ic];

    const float* b0 = bank + (size_t)((0 * COUT + oc) * CIN + ic) * NTAP;
    const float* b1 = bank + (size_t)((1 * COUT + oc) * CIN + ic) * NTAP;
    const float* b2 = bank + (size_t)((2 * COUT + oc) * CIN + ic) * NTAP;
    const float* b3 = bank + (size_t)((3 * COUT + oc) * CIN + ic) * NTAP;

    float v[NTAP];
    float ss = 0.0f;
#pragma unroll
    for (int k = 0; k < NTAP; ++k) {
        float t = f0 * b0[k] + f1 * b1[k] + f2 * b2[k] + f3 * b3[k];
        t *= m;
        v[k] = t;
        ss += t * t;
    }
    // reduce ss over all 64 lanes (full (ic,tap) sum for this (b,oc))
#pragma unroll
    for (int off = 32; off >= 1; off >>= 1) ss += __shfl_xor(ss, off, 64);
    const float d = rsqrtf(ss + EPS);

    float* o = mw + (size_t)(((b * COUT + oc) * CIN) + ic) * NTAP;
#pragma unroll
    for (int k = 0; k < NTAP; ++k) o[k] = v[k] * d;
}

// ---------------------------------------------------------------------------
// Kernel 2: direct grouped conv3d. grid=(DSZ z, COUT, BS), 256 threads.
// Block computes one (b, oc, z) output plane (32x32).
// Thread t: x = t&31, y0 = (t>>5)*4, computes 4 consecutive-y outputs.
// x slab (3 z-planes, zero-padded 34x34) staged in LDS per input channel.
// ---------------------------------------------------------------------------
__global__ __launch_bounds__(256) void conv3d_direct(
        const float* __restrict__ x,
        const float* __restrict__ mw,
        float* __restrict__ out) {
    const int z  = blockIdx.x;
    const int oc = blockIdx.y;
    const int b  = blockIdx.z;
    const int t  = threadIdx.x;
    const int xq = t & 31;
    const int y0 = (t >> 5) << 2;         // 0,4,8,...,28

    __shared__ float xs[3 * 34 * 34];     // [dz][yy][xx], yy/xx padded by 1

    // zero everything once (pads stay zero; interior overwritten each ic)
    for (int p = t; p < 3 * 34 * 34; p += 256) xs[p] = 0.0f;

    const float* wp = mw + (size_t)((b * COUT + oc) * CIN) * NTAP;
    const float* xb = x + (size_t)b * CIN * SPATIAL;

    float acc0 = 0.0f, acc1 = 0.0f, acc2 = 0.0f, acc3 = 0.0f;

    for (int ic = 0; ic < CIN; ++ic) {
        __syncthreads();
        // fill interior: 3 planes x 32 x 32 = 3072 values
        for (int p = t; p < 3072; p += 256) {
            const int dz  = p >> 10;
            const int rem = p & 1023;          // yy*32 + xx
            const int yy  = rem >> 5;
            const int xx  = rem & 31;
            const int zz  = z + dz - 1;
            float v = 0.0f;
            if (zz >= 0 && zz < DSZ) v = xb[(size_t)ic * SPATIAL + zz * 1024 + rem];
            xs[dz * 1156 + (yy + 1) * 34 + (xx + 1)] = v;
        }
        __syncthreads();

        float wr[NTAP];
#pragma unroll
        for (int k = 0; k < NTAP; ++k) wr[k] = wp[ic * NTAP + k];

#pragma unroll
        for (int dz = 0; dz < 3; ++dz) {
#pragma unroll
            for (int dx = 0; dx < 3; ++dx) {
                float v[6];
#pragma unroll
                for (int q = 0; q < 6; ++q)
                    v[q] = xs[dz * 1156 + (y0 + q) * 34 + (xq + dx)];
#pragma unroll
                for (int dy = 0; dy < 3; ++dy) {
                    const float wv = wr[dz * 9 + dy * 3 + dx];
                    acc0 += wv * v[0 + dy];
                    acc1 += wv * v[1 + dy];
                    acc2 += wv * v[2 + dy];
                    acc3 += wv * v[3 + dy];
                }
            }
        }
    }

    float* op = out + ((size_t)(b * COUT + oc) * DSZ + z) * 1024 + y0 * 32 + xq;
    op[0]  = acc0;
    op[32] = acc1;
    op[64] = acc2;
    op[96] = acc3;
}

// ---------------------------------------------------------------------------
extern "C" void kernel_launch(void* const* d_in, const int* in_sizes, int n_in,
                              void* d_out, int out_size, void* d_ws, size_t ws_size,
                              hipStream_t stream) {
    const float* x        = (const float*)d_in[0];
    const float* w        = (const float*)d_in[1];
    const float* filter_w = (const float*)d_in[2];
    const float* filter_b = (const float*)d_in[3];
    const float* mod_w    = (const float*)d_in[4];
    const float* mod_b    = (const float*)d_in[5];
    const float* bank     = (const float*)d_in[6];
    float* out = (float*)d_out;

    float* mw  = (float*)d_ws;
    float* fwt = mw + MW_ELEMS;
    float* mod = fwt + BS * NBANK;

    prep_style<<<BS, 64, 0, stream>>>(w, filter_w, filter_b, mod_w, mod_b, fwt, mod);
    prep_weights<<<dim3(COUT, BS), 64, 0, stream>>>(bank, fwt, mod, mw);
    conv3d_direct<<<dim3(DSZ, COUT, BS), 256, 0, stream>>>(x, mw, out);
}

// Round 2
// 89.576 us; speedup vs baseline: 24.6500x; 24.6500x over previous
//
#include <hip/hip_runtime.h>
#include <math.h>

#define BS 8
#define CIN 64
#define COUT 64
#define SDIM 512
#define NBANK 4
#define DSZ 32
#define SPATIAL (DSZ*DSZ*DSZ)
#define NTAP 27
#define CH 8                 // ic per chunk
#define NCH 8                // chunks (CH*NCH = CIN)
#define KPAD 232             // padded k-row per chunk: 28 taps * 8 ic + 8 pad
#define NKS 7                // MFMA K-steps per chunk (28 taps / 4 taps per K=32)
constexpr float EPS = 1e-8f;

typedef short bf16x8 __attribute__((ext_vector_type(8)));
typedef float f32x4 __attribute__((ext_vector_type(4)));

// ws layout: wA bf16 [BS][NCH][COUT][KPAD] then fwt f32[BS*4], mod f32[BS*64]
#define WA_ELEMS (BS*NCH*COUT*KPAD)

__device__ inline unsigned short bf16r(float f) {
    unsigned u = __float_as_uint(f);
    u = (u + 0x7fffu + ((u >> 16) & 1u)) >> 16;
    return (unsigned short)u;
}
__device__ inline unsigned pack2(float a, float b) {
    unsigned ua = __float_as_uint(a);
    unsigned ub = __float_as_uint(b);
    ua = (ua + 0x7fffu + ((ua >> 16) & 1u)) >> 16;
    ub = (ub + 0x7fffu + ((ub >> 16) & 1u)) & 0xffff0000u;
    return ua | ub;
}

// ---------------------------------------------------------------------------
// Kernel 0: per-sample style vectors. grid=BS, 64 threads.
// ---------------------------------------------------------------------------
__global__ void prep_style(const float* __restrict__ w,
                           const float* __restrict__ filter_w,
                           const float* __restrict__ filter_b,
                           const float* __restrict__ mod_w,
                           const float* __restrict__ mod_b,
                           float* __restrict__ fwt,
                           float* __restrict__ mod) {
    const int b = blockIdx.x;
    const int t = threadIdx.x;
    const float* wb = w + b * SDIM;
    __shared__ float lg[NBANK];

    if (t < NBANK) {
        float s = filter_b[t];
        const float* fr = filter_w + t * SDIM;
        for (int j = 0; j < SDIM; ++j) s += wb[j] * fr[j];
        lg[t] = s;
    }
    __syncthreads();
    if (t == 0) {
        float m = lg[0];
        for (int n = 1; n < NBANK; ++n) m = fmaxf(m, lg[n]);
        float e[NBANK];
        float s = 0.0f;
        for (int n = 0; n < NBANK; ++n) { e[n] = expf(lg[n] - m); s += e[n]; }
        for (int n = 0; n < NBANK; ++n) fwt[b * NBANK + n] = e[n] / s;
    }
    {
        float s = mod_b[t];
        const float* mr = mod_w + t * SDIM;
        for (int j = 0; j < SDIM; ++j) s += wb[j] * mr[j];
        mod[b * CIN + t] = s;
    }
}

// ---------------------------------------------------------------------------
// Kernel 1: blended+modulated+demodulated weights -> bf16, MFMA-ready layout
// wA[b][chunk][oc][k] with k = tap*8 + (ic&7); k in [216,232) zeroed.
// grid=(COUT, BS), 64 threads (lane = ic).
// ---------------------------------------------------------------------------
__global__ void prep_weights(const float* __restrict__ bank,
                             const float* __restrict__ fwt,
                             const float* __restrict__ mod,
                             unsigned short* __restrict__ wA) {
    const int oc = blockIdx.x;
    const int b  = blockIdx.y;
    const int ic = threadIdx.x;

    const float f0 = fwt[b * NBANK + 0];
    const float f1 = fwt[b * NBANK + 1];
    const float f2 = fwt[b * NBANK + 2];
    const float f3 = fwt[b * NBANK + 3];
    const float m  = mod[b * CIN + ic];

    const float* b0 = bank + (size_t)((0 * COUT + oc) * CIN + ic) * NTAP;
    const float* b1 = bank + (size_t)((1 * COUT + oc) * CIN + ic) * NTAP;
    const float* b2 = bank + (size_t)((2 * COUT + oc) * CIN + ic) * NTAP;
    const float* b3 = bank + (size_t)((3 * COUT + oc) * CIN + ic) * NTAP;

    float v[NTAP];
    float ss = 0.0f;
#pragma unroll
    for (int k = 0; k < NTAP; ++k) {
        float t = f0 * b0[k] + f1 * b1[k] + f2 * b2[k] + f3 * b3[k];
        t *= m;
        v[k] = t;
        ss += t * t;
    }
#pragma unroll
    for (int off = 32; off >= 1; off >>= 1) ss += __shfl_xor(ss, off, 64);
    const float d = rsqrtf(ss + EPS);

    const int chunk = ic >> 3, icl = ic & 7;
    unsigned short* row = wA + (size_t)(((b * NCH + chunk) * COUT) + oc) * KPAD;
#pragma unroll
    for (int k = 0; k < NTAP; ++k) row[k * CH + icl] = bf16r(v[k] * d);

    // zero the pad region [216,232) of every chunk row for this (b,oc):
    // thread ic zeroes 2 entries of chunk (ic>>3)
    unsigned short* rz = wA + (size_t)(((b * NCH + chunk) * COUT) + oc) * KPAD;
    rz[216 + icl * 2]     = 0;
    rz[216 + icl * 2 + 1] = 0;
}

// ---------------------------------------------------------------------------
// Kernel 2: implicit-GEMM conv3d via MFMA 16x16x32 bf16.
// grid = 256 blocks (bid%8 = b, bid/8 = z), 512 threads (8 waves).
// Block computes out[b][all 64 oc][z][32x32].
// LDS: xs[3 z'][34 y'][34 x'] texels of 8 bf16 (ic chunk), + A[64 oc][232 k].
// Wave w owns 4 oc-tiles x 8 sp-tiles (sp-tile = (y=w*4+(st>>1), x0=(st&1)*16)).
// ---------------------------------------------------------------------------
__global__ __launch_bounds__(512, 2) void conv3d_mfma(
        const float* __restrict__ x,
        const unsigned short* __restrict__ wA,
        float* __restrict__ out) {
    const int bid = blockIdx.x;
    const int b = bid & 7, z = bid >> 3;
    const int t  = threadIdx.x;
    const int ln = t & 15;           // n / m-row selector within fragment
    const int hi = (t >> 4) & 3;     // k-block selector
    const int wv = t >> 6;           // wave id 0..7

    __shared__ int4 smem[3468 + 1856];   // xs (3*34*34 texels) | A (64*232*2 B)
    int4* xs   = smem;
    int4* Alds = smem + 3468;
    char* Xb = (char*)xs;
    const char* Ab = (const char*)Alds;

    // per-lane tap byte-offsets (texel*16) for each K-step; tap = ks*4 + hi
    int offBb[NKS];
#pragma unroll
    for (int ks = 0; ks < NKS; ++ks) {
        int tap = ks * 4 + hi;
        if (tap > 26) tap = 0;       // tap 27: A is zero, address just needs validity
        int dz = tap / 9, r = tap - dz * 9, dy = r / 3, dx = r - dy * 3;
        offBb[ks] = (dz * 1156 + dy * 34 + dx) * 16;
    }
    int baseBb[8];
#pragma unroll
    for (int st = 0; st < 8; ++st)
        baseBb[st] = ((wv * 4 + (st >> 1)) * 34 + (st & 1) * 16 + ln) * 16;
    int baseA[4];
#pragma unroll
    for (int at = 0; at < 4; ++at)
        baseA[at] = ((at * 16 + ln) * KPAD + hi * CH) * 2;

    // zero-fill xs (halo stays zero forever; interior rewritten per chunk)
    const int4 z4 = make_int4(0, 0, 0, 0);
    for (int p = t; p < 3468; p += 512) xs[p] = z4;

    const float* xb = x + (size_t)b * CIN * SPATIAL;
    const unsigned short* wAb = wA + (size_t)b * NCH * COUT * KPAD;

    f32x4 acc[4][8];
#pragma unroll
    for (int i = 0; i < 4; ++i)
#pragma unroll
        for (int j = 0; j < 8; ++j) acc[i][j] = (f32x4){0.f, 0.f, 0.f, 0.f};

    for (int c = 0; c < NCH; ++c) {
        __syncthreads();             // previous chunk's MFMA reads done

        // ---- stage A chunk: 64*232*2 = 29696 B = 1856 int4 ----
        {
            const int4* srcA = (const int4*)(wAb + (size_t)c * COUT * KPAD);
#pragma unroll
            for (int it = 0; it < 4; ++it) {
                int p = t + it * 512;
                if (p < 1856) Alds[p] = srcA[p];
            }
        }

        // ---- stage x chunk: 3 planes x 32x32 interior texels, 8 ic each ----
#pragma unroll
        for (int rep = 0; rep < 6; ++rep) {
            int p = t + rep * 512;           // 0..3071
            int dz = p >> 10, rem = p & 1023;
            int zz = z + dz - 1;
            int4 v = z4;
            if (zz >= 0 && zz < DSZ) {
                const float* s = xb + (size_t)c * CH * SPATIAL + (size_t)zz * 1024 + rem;
                float f0 = s[0 * SPATIAL], f1 = s[1 * SPATIAL];
                float f2 = s[2 * SPATIAL], f3 = s[3 * SPATIAL];
                float f4 = s[4 * SPATIAL], f5 = s[5 * SPATIAL];
                float f6 = s[6 * SPATIAL], f7 = s[7 * SPATIAL];
                v.x = (int)pack2(f0, f1);
                v.y = (int)pack2(f2, f3);
                v.z = (int)pack2(f4, f5);
                v.w = (int)pack2(f6, f7);
            }
            int yy = rem >> 5, xx = rem & 31;
            xs[dz * 1156 + (yy + 1) * 34 + (xx + 1)] = v;
        }
        __syncthreads();

        // ---- MFMA: 7 K-steps, each K=32 = taps {4ks..4ks+3} x 8 ic ----
#pragma unroll
        for (int ks = 0; ks < NKS; ++ks) {
            bf16x8 a[4];
#pragma unroll
            for (int at = 0; at < 4; ++at)
                a[at] = *(const bf16x8*)(Ab + baseA[at] + ks * 64);
            bf16x8 bf[8];
#pragma unroll
            for (int st = 0; st < 8; ++st)
                bf[st] = *(const bf16x8*)(Xb + baseBb[st] + offBb[ks]);
#pragma unroll
            for (int at = 0; at < 4; ++at)
#pragma unroll
                for (int st = 0; st < 8; ++st)
                    acc[at][st] = __builtin_amdgcn_mfma_f32_16x16x32_bf16(
                        a[at], bf[st], acc[at][st], 0, 0, 0);
        }
    }

    // ---- epilogue: D layout col=lane&15, row=(lane>>4)*4+reg ----
    float* ob = out + (size_t)b * COUT * SPATIAL + (size_t)z * 1024;
#pragma unroll
    for (int at = 0; at < 4; ++at) {
        int oc = at * 16 + hi * 4;
#pragma unroll
        for (int st = 0; st < 8; ++st) {
            int sp = (wv * 4 + (st >> 1)) * 32 + (st & 1) * 16 + ln;
#pragma unroll
            for (int r = 0; r < 4; ++r)
                ob[(size_t)(oc + r) * SPATIAL + sp] = acc[at][st][r];
        }
    }
}

// ---------------------------------------------------------------------------
extern "C" void kernel_launch(void* const* d_in, const int* in_sizes, int n_in,
                              void* d_out, int out_size, void* d_ws, size_t ws_size,
                              hipStream_t stream) {
    const float* x        = (const float*)d_in[0];
    const float* w        = (const float*)d_in[1];
    const float* filter_w = (const float*)d_in[2];
    const float* filter_b = (const float*)d_in[3];
    const float* mod_w    = (const float*)d_in[4];
    const float* mod_b    = (const float*)d_in[5];
    const float* bank     = (const float*)d_in[6];
    float* out = (float*)d_out;

    unsigned short* wA = (unsigned short*)d_ws;
    float* fwt = (float*)((char*)d_ws + (size_t)WA_ELEMS * 2);
    float* mod = fwt + BS * NBANK;

    prep_style<<<BS, 64, 0, stream>>>(w, filter_w, filter_b, mod_w, mod_b, fwt, mod);
    prep_weights<<<dim3(COUT, BS), 64, 0, stream>>>(bank, fwt, mod, wA);
    conv3d_mfma<<<256, 512, 0, stream>>>(x, wA, out);
}